// Round 7
// baseline (1490.379 us; speedup 1.0000x reference)
//
#include <hip/hip_runtime.h>

typedef unsigned short u16;
typedef __bf16 bf16x8 __attribute__((ext_vector_type(8)));
typedef float floatx4 __attribute__((ext_vector_type(4)));

__device__ __forceinline__ float u2f(u16 u) { return __uint_as_float(((unsigned)u) << 16); }
__device__ __forceinline__ u16 f2u(float f) {
    unsigned x = __float_as_uint(f);
    x += 0x7fffu + ((x >> 16) & 1u);   // RNE to bf16
    return (u16)(x >> 16);
}

// ---------------- prep kernels ----------------
__global__ void k_fill_f32(float* p, float v, int n) {
    int i = blockIdx.x * blockDim.x + threadIdx.x;
    if (i < n) p[i] = v;
}
__global__ void k_fill_i32(int* p, int v, int n) {
    int i = blockIdx.x * blockDim.x + threadIdx.x;
    if (i < n) p[i] = v;
}
__global__ void k_deg_accum(const int* __restrict__ dst, const float* __restrict__ ew,
                            float* __restrict__ deg, int E) {
    int e = blockIdx.x * blockDim.x + threadIdx.x;
    if (e < E) atomicAdd(&deg[dst[e]], ew[e]);
}
__global__ void k_finish_deg(const float* __restrict__ deg, float* __restrict__ dinv,
                             float* __restrict__ dinv2, int n) {
    int i = blockIdx.x * blockDim.x + threadIdx.x;
    if (i < n) { float r = rsqrtf(deg[i]); dinv[i] = r; dinv2[i] = r * r; }
}
__global__ void k_count(const int* __restrict__ dst, int* __restrict__ cnt, int E) {
    int e = blockIdx.x * blockDim.x + threadIdx.x;
    if (e < E) atomicAdd(&cnt[dst[e]], 1);
}
// single-block exclusive scan over n=16384 counts -> off[0..n]
__global__ void k_scan(const int* __restrict__ cnt, int* __restrict__ off, int n) {
    __shared__ int sh[1024];
    int t = threadIdx.x;
    const int per = n / 1024;   // 16
    int base = t * per;
    int loc[16];
    int s = 0;
    for (int j = 0; j < per; ++j) { loc[j] = s; s += cnt[base + j]; }
    sh[t] = s;
    __syncthreads();
    for (int d = 1; d < 1024; d <<= 1) {
        int v = (t >= d) ? sh[t - d] : 0;
        __syncthreads();
        sh[t] += v;
        __syncthreads();
    }
    int prev = (t == 0) ? 0 : sh[t - 1];
    for (int j = 0; j < per; ++j) off[base + j] = prev + loc[j];
    if (t == 1023) off[n] = prev + s;
}
__global__ void k_fill_csr(const int* __restrict__ src, const int* __restrict__ dst,
                           const float* __restrict__ ew, const float* __restrict__ dinv,
                           const int* __restrict__ off, int* __restrict__ cur,
                           int* __restrict__ csr_src, float* __restrict__ csr_w, int E) {
    int e = blockIdx.x * blockDim.x + threadIdx.x;
    if (e < E) {
        int d = dst[e], s = src[e];
        int p = off[d] + atomicAdd(&cur[d], 1);
        csr_src[p] = s;
        csr_w[p] = dinv[s] * ew[e] * dinv[d];
    }
}
// W[K][M] (f32) -> Wt[Mpad][K] (bf16), zero-filled for m >= M. grid(Mpad/32, K/32), block(32,8)
__global__ void k_transpose(const float* __restrict__ W, u16* __restrict__ Wt, int K, int M) {
    __shared__ u16 tile[32][33];
    int m0 = blockIdx.x * 32, k0 = blockIdx.y * 32;
    int tx = threadIdx.x, ty = threadIdx.y;
    #pragma unroll
    for (int rr = 0; rr < 4; ++rr) {
        int r = ty + rr * 8;
        int m = m0 + tx, k = k0 + r;
        tile[r][tx] = (m < M) ? f2u(W[(size_t)k * M + m]) : (u16)0;
    }
    __syncthreads();
    #pragma unroll
    for (int rr = 0; rr < 4; ++rr) {
        int r = ty + rr * 8;
        Wt[(size_t)(m0 + r) * K + k0 + tx] = tile[tx][r];
    }
}

// ---------------- async global -> LDS (16B/lane, wave-uniform LDS base) ----------------
__device__ __forceinline__ void gload16(const u16* g, void* l) {
    typedef __attribute__((address_space(1))) void* gas_t;
    typedef __attribute__((address_space(3))) void* las_t;
    __builtin_amdgcn_global_load_lds((gas_t)g, (las_t)l, 16, 0, 0);
}

// ---------------- GEMM: C[16384 x Nreal] = A[16384 x K] * Bt[Npad x K]^T ----------------
// 256x256 tile, BK=64, 8 waves (2Mx4N at 16-granularity), 128 KiB LDS as 8 half-tile
// slots of 16 KiB.  FULLY PIPELINED 4-phase schedule: every ds_read is issued ONE
// PHASE before its MFMA consumes it, so the LDS pipe drains under the matrix pipe:
//   p0: read b23(t)    [Bh1(t), 4]   used G1@p1     lgkm(4)  retires aX,b01 (from p2/p3 prev)
//   p1: read aY(t)     [Ah1(t), 8]   used G2,G3     lgkm(8)  retires b23
//   p2: read aX(t+1)   [Ah0(t+1),8]  used G0'@p0'   lgkm(8)  retires aY
//   p3: read b01(t+1)  [Bh0(t+1),4]  used G0',G2'   lgkm(12) no-op (nothing older)
// MFMA groups (order identical to round 6 -> same accumulation order/absmax):
//   G0(aX,b01)@p0, G1(aX,b23)@p1, G2(aY,b01)@p2, G3(aY,b23)@p3.
// All operand sets single-buffered (each overwritten >=1 phase after last use).
// vmcnt(6) at p1-exit certifies Ah0(t+1),Bh0(t+1) (staged 3-4 phases prior);
// vmcnt(6) at p3-exit certifies Bh1(t+1),Ah1(t+1).  Stage plan identical to round 6.
// LDS XOR-swizzle byte^=(row&7)<<4 via inverse-permuted global source + swizzled reads.
// EPI: 0 = none, 1 = +bias, 2 = relu(+bias)
#define PHASE_ENTER(lgk) do {                                 \
    __builtin_amdgcn_sched_barrier(0);                        \
    __builtin_amdgcn_s_barrier();                             \
    asm volatile("s_waitcnt lgkmcnt(" #lgk ")" ::: "memory"); \
    __builtin_amdgcn_sched_barrier(0);                        \
    __builtin_amdgcn_s_setprio(1);                            \
} while (0)
#define PHASE_EXIT() do {                                     \
    __builtin_amdgcn_s_setprio(0);                            \
    __builtin_amdgcn_sched_barrier(0);                        \
    __builtin_amdgcn_s_barrier();                             \
    __builtin_amdgcn_sched_barrier(0);                        \
} while (0)
#define PHASE_EXIT_VM(n) do {                                 \
    __builtin_amdgcn_s_setprio(0);                            \
    __builtin_amdgcn_sched_barrier(0);                        \
    asm volatile("s_waitcnt vmcnt(" #n ")" ::: "memory");     \
    __builtin_amdgcn_sched_barrier(0);                        \
    __builtin_amdgcn_s_barrier();                             \
    __builtin_amdgcn_sched_barrier(0);                        \
} while (0)

#define MFMA_G(AR, AS, BS, NB)                                                    \
    _Pragma("unroll")                                                             \
    for (int mi = 0; mi < 4; ++mi) {                                              \
        _Pragma("unroll")                                                         \
        for (int ni = 0; ni < 2; ++ni) {                                          \
            acc[(AR) + mi][(NB) + ni] = __builtin_amdgcn_mfma_f32_16x16x32_bf16(  \
                AS[mi][0], BS[ni][0], acc[(AR) + mi][(NB) + ni], 0, 0, 0);        \
            acc[(AR) + mi][(NB) + ni] = __builtin_amdgcn_mfma_f32_16x16x32_bf16(  \
                AS[mi][1], BS[ni][1], acc[(AR) + mi][(NB) + ni], 0, 0, 0);        \
        }                                                                         \
    }

#define RD_A(DST, BASEOFF)                                                        \
    _Pragma("unroll")                                                             \
    for (int mi = 0; mi < 4; ++mi) {                                              \
        DST[mi][0] = *(const bf16x8*)(smemc + (BASEOFF) + mi * 4096 + aO0);       \
        DST[mi][1] = *(const bf16x8*)(smemc + (BASEOFF) + mi * 4096 + aO1);       \
    }
#define RD_B(DST, BASEOFF)                                                        \
    _Pragma("unroll")                                                             \
    for (int ni = 0; ni < 2; ++ni) {                                              \
        DST[ni][0] = *(const bf16x8*)(smemc + (BASEOFF) + ni * 8192 + bO0);       \
        DST[ni][1] = *(const bf16x8*)(smemc + (BASEOFF) + ni * 8192 + bO1);       \
    }

// One K-tile, parity P (= TT&1) and next-tile parity PN as compile-time constants.
#define KTILE(TT, P, PN)                                                          \
    /* ---- p0 ---- */                                                            \
    RD_B(b23, (P) * 65536 + 32768);                                               \
    stage((TT) + 1, 3);                                                           \
    PHASE_ENTER(4);                                                               \
    MFMA_G(0, aX, b01, 0);                                                        \
    PHASE_EXIT();                                                                 \
    /* ---- p1 ---- */                                                            \
    RD_A(aY, (P) * 65536 + 49152);                                                \
    stage((TT) + 2, 0);                                                           \
    PHASE_ENTER(8);                                                               \
    MFMA_G(0, aX, b23, 2);                                                        \
    PHASE_EXIT_VM(6);                                                             \
    /* ---- p2 ---- */                                                            \
    RD_A(aX, (PN) * 65536 + 0);                                                   \
    stage((TT) + 2, 1);                                                           \
    PHASE_ENTER(8);                                                               \
    MFMA_G(4, aY, b01, 0);                                                        \
    PHASE_EXIT();                                                                 \
    /* ---- p3 ---- */                                                            \
    RD_B(b01, (PN) * 65536 + 16384);                                              \
    stage((TT) + 2, 2);                                                           \
    PHASE_ENTER(12);                                                              \
    MFMA_G(4, aY, b23, 2);                                                        \
    PHASE_EXIT_VM(6);

template <int EPI, typename CT>
__global__ __launch_bounds__(512, 2)
void gemm256(const u16* __restrict__ A, const u16* __restrict__ Bt,
             const float* __restrict__ bias, CT* __restrict__ C,
             int K, int Nreal, int ldc, int nbx) {
    __shared__ __align__(16) u16 smem[65536];   // 128 KiB = 8 slots x 16 KiB

    // XCD-aware block swizzle (guarded: only when grid is a multiple of 8 -> bijective)
    const int nb = (int)gridDim.x;
    int id = (int)blockIdx.x;
    if ((nb & 7) == 0) id = (id & 7) * (nb >> 3) + (id >> 3);
    const int bx = id % nbx, by = id / nbx;
    const size_t row0 = (size_t)by * 256, col0 = (size_t)bx * 256;

    const int t = threadIdx.x;
    const int lane = t & 63, wave = t >> 6;     // 8 waves
    const int wm = wave >> 2, wn = wave & 3;    // 2 x 4
    const int quad = lane >> 4, l16 = lane & 15;
    const int NT = K >> 6;                      // K-tiles of 64 (even for all layers)

    // --- staging source pointers (per thread, insts i=0,1) ---
    const u16* gA[2]; const u16* gB[2];
    #pragma unroll
    for (int i = 0; i < 2; ++i) {
        int c = wave * 128 + i * 64 + lane;
        int lc = c ^ ((c >> 3) & 7);            // chunk-level inverse of byte^=(row&7)<<4
        int srow = lc >> 3, k8 = lc & 7;
        gA[i] = A + (row0 + srow) * (size_t)K + k8 * 8;
        gB[i] = Bt + (col0 + srow) * (size_t)K + k8 * 8;
    }
    const int ldst = wave * 2048;               // this wave's byte base within a slot
    const size_t halfK = (size_t)128 * K;       // element offset of rows 128..255

    auto stage = [&](int tile, int j) {         // j: 0=A.h0 1=B.h0 2=B.h1 3=A.h1
        int tw = tile >= NT ? tile - NT : tile; // wrap past end (data never read)
        const size_t roff = (j >= 2 ? halfK : (size_t)0) + (size_t)tw * 64;
        char* lb = (char*)smem + ((((tile & 1) << 2) + j) << 14) + ldst;
        if (j == 0 || j == 3) {
            gload16(gA[0] + roff, lb);
            gload16(gA[1] + roff, lb + 1024);
        } else {
            gload16(gB[0] + roff, lb);
            gload16(gB[1] + roff, lb + 1024);
        }
    };

    // --- ds_read lane-offset components (slot-relative bytes, swizzled) ---
    const char* smemc = (const char*)smem;
    const int swz = (l16 & 7) << 4;
    const int aO0 = (wm * 16 + l16) * 128 + ((quad * 16) ^ swz);
    const int aO1 = (wm * 16 + l16) * 128 + ((64 + quad * 16) ^ swz);
    const int bO0 = (wn * 16 + l16) * 128 + ((quad * 16) ^ swz);
    const int bO1 = (wn * 16 + l16) * 128 + ((64 + quad * 16) ^ swz);

    floatx4 acc[8][4];
    #pragma unroll
    for (int i = 0; i < 8; ++i)
        #pragma unroll
        for (int j = 0; j < 4; ++j) acc[i][j] = (floatx4){0.f, 0.f, 0.f, 0.f};
    bf16x8 aX[4][2];   // A.h0 of current tile (refilled @p2 with next tile's)
    bf16x8 aY[4][2];   // A.h1 of current tile (refilled @p1)
    bf16x8 b01[2][2];  // B cols ni0-1 (refilled @p3 with next tile's)
    bf16x8 b23[2][2];  // B cols ni2-3 (refilled @p0)

    // --- prologue: stage halves o0..o6 (tile0 complete + tile1 {Ah0,Bh0,Bh1}) ---
    stage(0, 0); stage(0, 1); stage(0, 2); stage(0, 3);
    __builtin_amdgcn_sched_barrier(0);
    asm volatile("s_waitcnt vmcnt(4)" ::: "memory");
    __builtin_amdgcn_sched_barrier(0);
    stage(1, 0); stage(1, 1); stage(1, 2);
    __builtin_amdgcn_sched_barrier(0);
    asm volatile("s_waitcnt vmcnt(6)" ::: "memory");   // tile 0 fully resident
    __builtin_amdgcn_sched_barrier(0);
    __builtin_amdgcn_s_barrier();
    __builtin_amdgcn_sched_barrier(0);

    // pre-reads (emulate p2/p3 of tile -1): aX <- A.h0(0), b01 <- B.h0(0)
    RD_A(aX, 0);
    RD_B(b01, 16384);

    for (int tt = 0; tt < NT; tt += 2) {
        KTILE(tt, 0, 1)
        KTILE(tt + 1, 1, 0)
    }

    // ---- epilogue: C/D layout (m89-verified): col = lane&15, row = quad*4 + r
    #pragma unroll
    for (int ni = 0; ni < 4; ++ni) {
        const int col = (int)col0 + ni * 64 + wn * 16 + l16;
        if (col >= Nreal) continue;
        const float bv = (EPI != 0) ? bias[col] : 0.f;
        #pragma unroll
        for (int mi = 0; mi < 8; ++mi) {
            #pragma unroll
            for (int r = 0; r < 4; ++r) {
                size_t row = row0 + mi * 32 + wm * 16 + quad * 4 + r;
                float v = acc[mi][ni][r] + bv;
                if (EPI == 2) v = fmaxf(v, 0.f);
                if constexpr (sizeof(CT) == 2) C[row * (size_t)ldc + col] = (CT)f2u(v);
                else                           C[row * (size_t)ldc + col] = (CT)v;
            }
        }
    }
}

// 8-wide row load -> f32, for f32 or bf16 source
__device__ __forceinline__ void load8_f(const float* p, float* v) {
    float4 a = *(const float4*)p;
    float4 b = *(const float4*)(p + 4);
    v[0] = a.x; v[1] = a.y; v[2] = a.z; v[3] = a.w;
    v[4] = b.x; v[5] = b.y; v[6] = b.z; v[7] = b.w;
}
__device__ __forceinline__ void load8_b(const u16* p, float* v) {
    uint4 a = *(const uint4*)p;
    const u16* ap = (const u16*)&a;
    #pragma unroll
    for (int j = 0; j < 8; ++j) v[j] = u2f(ap[j]);
}

// ---------- aggregation (pre-GEMM): Xa[i] = dinv2[i]*X[i] + sum_e w_e * X[src_e]; Xa bf16 ----------
template <typename XT>
__global__ __launch_bounds__(256)
void k_agg_pre(const XT* __restrict__ X, const int* __restrict__ off,
               const int* __restrict__ csr_src, const float* __restrict__ csr_w,
               const float* __restrict__ dinv2, u16* __restrict__ Xa, int F) {
    const int i = blockIdx.x;
    const int e0 = off[i], e1 = off[i + 1];
    const float d2 = dinv2[i];
    const int stride = blockDim.x * 8;
    for (int f = threadIdx.x * 8; f < F; f += stride) {
        float acc[8], hv[8];
        if constexpr (sizeof(XT) == 2) load8_b((const u16*)&X[(size_t)i * F + f], hv);
        else                           load8_f((const float*)&X[(size_t)i * F + f], hv);
        #pragma unroll
        for (int j = 0; j < 8; ++j) acc[j] = d2 * hv[j];
        for (int e = e0; e < e1; ++e) {
            int s = csr_src[e];
            float w = csr_w[e];
            float sv[8];
            if constexpr (sizeof(XT) == 2) load8_b((const u16*)&X[(size_t)s * F + f], sv);
            else                           load8_f((const float*)&X[(size_t)s * F + f], sv);
            #pragma unroll
            for (int j = 0; j < 8; ++j) acc[j] = fmaf(w, sv[j], acc[j]);
        }
        uint4 ov;
        u16* op = (u16*)&ov;
        #pragma unroll
        for (int j = 0; j < 8; ++j) op[j] = f2u(acc[j]);
        *(uint4*)&Xa[(size_t)i * F + f] = ov;
    }
}

// ---------- aggregation (post-GEMM): X[i] = relu(b + dinv2[i]*H[i] + sum_e w_e*H[src_e]) ----------
__global__ __launch_bounds__(256)
void k_agg_post(const u16* __restrict__ H, const int* __restrict__ off,
                const int* __restrict__ csr_src, const float* __restrict__ csr_w,
                const float* __restrict__ dinv2, const float* __restrict__ bias,
                u16* __restrict__ X, int F) {
    const int i = blockIdx.x;
    const int e0 = off[i], e1 = off[i + 1];
    const float d2 = dinv2[i];
    const int stride = blockDim.x * 8;
    for (int f = threadIdx.x * 8; f < F; f += stride) {
        float acc[8], hv[8];
        load8_b(&H[(size_t)i * F + f], hv);
        #pragma unroll
        for (int j = 0; j < 8; ++j) acc[j] = fmaf(d2, hv[j], bias[f + j]);
        for (int e = e0; e < e1; ++e) {
            int s = csr_src[e];
            float w = csr_w[e];
            float sv[8];
            load8_b(&H[(size_t)s * F + f], sv);
            #pragma unroll
            for (int j = 0; j < 8; ++j) acc[j] = fmaf(w, sv[j], acc[j]);
        }
        uint4 ov;
        u16* op = (u16*)&ov;
        #pragma unroll
        for (int j = 0; j < 8; ++j) op[j] = f2u(fmaxf(acc[j], 0.f));
        *(uint4*)&X[(size_t)i * F + f] = ov;
    }
}

// ---------------- launch ----------------
extern "C" void kernel_launch(void* const* d_in, const int* in_sizes, int n_in,
                              void* d_out, int out_size, void* d_ws, size_t ws_size,
                              hipStream_t stream) {
    const int N = 16384, E = 65536;
    const float* x   = (const float*)d_in[0];
    const int*   src = (const int*)d_in[1];
    const int*   dst = (const int*)d_in[2];
    const float* ew  = (const float*)d_in[3];
    const float* W[5] = {(const float*)d_in[4], (const float*)d_in[6], (const float*)d_in[8],
                         (const float*)d_in[10], (const float*)d_in[12]};
    const float* b[5] = {(const float*)d_in[5], (const float*)d_in[7], (const float*)d_in[9],
                         (const float*)d_in[11], (const float*)d_in[13]};
    static const int Kd[5] = {512, 1024, 2048, 4096, 2048};   // GEMM K per layer
    static const int Md[5] = {1024, 2048, 4096, 2048, 1000};  // real out cols
    static const int Mp[5] = {1024, 2048, 4096, 2048, 1024};  // padded out cols

    char* ws = (char*)d_ws;
    size_t o = 0;
    auto alloc = [&](size_t bytes) -> void* {
        void* p = ws + o;
        o = (o + bytes + 255) & ~(size_t)255;
        return p;
    };
    u16* P = (u16*)alloc((size_t)N * 4096 * 2);   // 128 MiB
    u16* Q = (u16*)alloc((size_t)N * 2048 * 2);   //  64 MiB
    u16* Wt[5];
    for (int i = 0; i < 5; ++i) Wt[i] = (u16*)alloc((size_t)Mp[i] * Kd[i] * 2);
    float* deg   = (float*)alloc(N * 4);
    float* dinv  = (float*)alloc(N * 4);
    float* dinv2 = (float*)alloc(N * 4);
    int* cnt     = (int*)alloc(N * 4);
    int* cur     = (int*)alloc(N * 4);
    int* off     = (int*)alloc((N + 1) * 4);
    int* csr_src = (int*)alloc(E * 4);
    float* csr_w = (float*)alloc(E * 4);
    (void)ws_size; (void)in_sizes; (void)n_in; (void)out_size;

    // graph prep
    k_fill_f32<<<N / 256, 256, 0, stream>>>(deg, 1.0f, N);
    k_fill_i32<<<N / 256, 256, 0, stream>>>(cnt, 0, N);
    k_fill_i32<<<N / 256, 256, 0, stream>>>(cur, 0, N);
    k_deg_accum<<<E / 256, 256, 0, stream>>>(dst, ew, deg, E);
    k_finish_deg<<<N / 256, 256, 0, stream>>>(deg, dinv, dinv2, N);
    k_count<<<E / 256, 256, 0, stream>>>(dst, cnt, E);
    k_scan<<<1, 1024, 0, stream>>>(cnt, off, N);
    k_fill_csr<<<E / 256, 256, 0, stream>>>(src, dst, ew, dinv, off, cur, csr_src, csr_w, E);

    // weight transposes f32 -> bf16 (pad Wout cols 1000 -> 1024 with zeros)
    for (int i = 0; i < 5; ++i)
        k_transpose<<<dim3(Mp[i] / 32, Kd[i] / 32), dim3(32, 8), 0, stream>>>(W[i], Wt[i], Kd[i], Md[i]);

    const int MT = N / 256;   // 64 row tiles

    // L1..L3: agg-first (A-hat linear => agg(X W) = (agg X) W), bias+relu in GEMM epilogue
    k_agg_pre<float><<<N, 64, 0, stream>>>(x, off, csr_src, csr_w, dinv2, Q, 512);
    gemm256<2, u16><<<dim3((Mp[0] / 256) * MT), 512, 0, stream>>>(Q, Wt[0], b[0], P, Kd[0], Md[0], Md[0], Mp[0] / 256);
    k_agg_pre<u16><<<N, 128, 0, stream>>>(P, off, csr_src, csr_w, dinv2, Q, 1024);
    gemm256<2, u16><<<dim3((Mp[1] / 256) * MT), 512, 0, stream>>>(Q, Wt[1], b[1], P, Kd[1], Md[1], Md[1], Mp[1] / 256);
    k_agg_pre<u16><<<N, 256, 0, stream>>>(P, off, csr_src, csr_w, dinv2, Q, 2048);
    gemm256<2, u16><<<dim3((Mp[2] / 256) * MT), 512, 0, stream>>>(Q, Wt[2], b[2], P, Kd[2], Md[2], Md[2], Mp[2] / 256);
    // L4: GEMM-then-agg (agg at 2048 instead of 4096)
    gemm256<0, u16><<<dim3((Mp[3] / 256) * MT), 512, 0, stream>>>(P, Wt[3], nullptr, Q, Kd[3], Md[3], Md[3], Mp[3] / 256);
    k_agg_post<<<N, 256, 0, stream>>>(Q, off, csr_src, csr_w, dinv2, b[3], P, 2048);
    // L5: output projection -> d_out f32 (Nreal=1000, ldc=1000)
    gemm256<1, float><<<dim3((Mp[4] / 256) * MT), 512, 0, stream>>>(P, Wt[4], b[4], (float*)d_out, Kd[4], Md[4], 1000, Mp[4] / 256);
}

// Round 8
// 970.111 us; speedup vs baseline: 1.5363x; 1.5363x over previous
//
#include <hip/hip_runtime.h>

typedef unsigned short u16;
typedef __bf16 bf16x8 __attribute__((ext_vector_type(8)));
typedef float floatx4 __attribute__((ext_vector_type(4)));

__device__ __forceinline__ float u2f(u16 u) { return __uint_as_float(((unsigned)u) << 16); }
__device__ __forceinline__ u16 f2u(float f) {
    unsigned x = __float_as_uint(f);
    x += 0x7fffu + ((x >> 16) & 1u);   // RNE to bf16
    return (u16)(x >> 16);
}

// ---------------- prep kernels ----------------
__global__ void k_fill_f32(float* p, float v, int n) {
    int i = blockIdx.x * blockDim.x + threadIdx.x;
    if (i < n) p[i] = v;
}
__global__ void k_fill_i32(int* p, int v, int n) {
    int i = blockIdx.x * blockDim.x + threadIdx.x;
    if (i < n) p[i] = v;
}
__global__ void k_deg_accum(const int* __restrict__ dst, const float* __restrict__ ew,
                            float* __restrict__ deg, int E) {
    int e = blockIdx.x * blockDim.x + threadIdx.x;
    if (e < E) atomicAdd(&deg[dst[e]], ew[e]);
}
__global__ void k_finish_deg(const float* __restrict__ deg, float* __restrict__ dinv,
                             float* __restrict__ dinv2, int n) {
    int i = blockIdx.x * blockDim.x + threadIdx.x;
    if (i < n) { float r = rsqrtf(deg[i]); dinv[i] = r; dinv2[i] = r * r; }
}
__global__ void k_count(const int* __restrict__ dst, int* __restrict__ cnt, int E) {
    int e = blockIdx.x * blockDim.x + threadIdx.x;
    if (e < E) atomicAdd(&cnt[dst[e]], 1);
}
// single-block exclusive scan over n=16384 counts -> off[0..n]
__global__ void k_scan(const int* __restrict__ cnt, int* __restrict__ off, int n) {
    __shared__ int sh[1024];
    int t = threadIdx.x;
    const int per = n / 1024;   // 16
    int base = t * per;
    int loc[16];
    int s = 0;
    for (int j = 0; j < per; ++j) { loc[j] = s; s += cnt[base + j]; }
    sh[t] = s;
    __syncthreads();
    for (int d = 1; d < 1024; d <<= 1) {
        int v = (t >= d) ? sh[t - d] : 0;
        __syncthreads();
        sh[t] += v;
        __syncthreads();
    }
    int prev = (t == 0) ? 0 : sh[t - 1];
    for (int j = 0; j < per; ++j) off[base + j] = prev + loc[j];
    if (t == 1023) off[n] = prev + s;
}
__global__ void k_fill_csr(const int* __restrict__ src, const int* __restrict__ dst,
                           const float* __restrict__ ew, const float* __restrict__ dinv,
                           const int* __restrict__ off, int* __restrict__ cur,
                           int* __restrict__ csr_src, float* __restrict__ csr_w, int E) {
    int e = blockIdx.x * blockDim.x + threadIdx.x;
    if (e < E) {
        int d = dst[e], s = src[e];
        int p = off[d] + atomicAdd(&cur[d], 1);
        csr_src[p] = s;
        csr_w[p] = dinv[s] * ew[e] * dinv[d];
    }
}
// W[K][M] (f32) -> Wt[Mpad][K] (bf16), zero-filled for m >= M. grid(Mpad/32, K/32), block(32,8)
__global__ void k_transpose(const float* __restrict__ W, u16* __restrict__ Wt, int K, int M) {
    __shared__ u16 tile[32][33];
    int m0 = blockIdx.x * 32, k0 = blockIdx.y * 32;
    int tx = threadIdx.x, ty = threadIdx.y;
    #pragma unroll
    for (int rr = 0; rr < 4; ++rr) {
        int r = ty + rr * 8;
        int m = m0 + tx, k = k0 + r;
        tile[r][tx] = (m < M) ? f2u(W[(size_t)k * M + m]) : (u16)0;
    }
    __syncthreads();
    #pragma unroll
    for (int rr = 0; rr < 4; ++rr) {
        int r = ty + rr * 8;
        Wt[(size_t)(m0 + r) * K + k0 + tx] = tile[tx][r];
    }
}

// ---------------- async global -> LDS (16B/lane, wave-uniform LDS base) ----------------
__device__ __forceinline__ void gload16(const u16* g, void* l) {
    typedef __attribute__((address_space(1))) void* gas_t;
    typedef __attribute__((address_space(3))) void* las_t;
    __builtin_amdgcn_global_load_lds((gas_t)g, (las_t)l, 16, 0, 0);
}

// ---------------- GEMM: C[16384 x Nreal] = A[16384 x K] * Bt[Npad x K]^T ----------------
// 256x256 tile, BK=64, 8 waves (2Mx4N at 16-granularity), 128 KiB LDS as 8 half-tile
// slots of 16 KiB.  Round-6 register structure (a[4][2], b[4][2] -- 64 frag VGPRs,
// no spill) with reads moved ONE PHASE EARLY *inside* the MFMA clusters:
// each ds_read is issued immediately after the last MFMA consuming its destination
// register's old value (register WAR orders it; completion hides under the remaining
// MFMAs + exit barrier; drained by the next phase's lgkmcnt(0)).
//   p0: G0(aH0 x b01); interleaved read b23 <- Bh1(t)      (b23 dead since prev p3)
//   p1: G1(aH0 x b23); per-mi replace a[mi] <- Ah1(t)      exit: vmcnt(6)
//   p2: G2(aH1 x b01, acc4+); tail read b01 <- Bh0(t+1)
//   p3: G3(aH1 x b23, acc4+); per-mi replace a[mi] <- Ah0(t+1)  exit: vmcnt(6)
// vmcnt ledger (2 loads/stage; 6 outstanding at tile entry -- invariant):
//   p1-exit vmcnt(6) retires S(t+1,Ah0),S(t+1,Bh0) -> certifies p2's b01(t+1) and
//   p3's a(t+1) reads; p3-exit vmcnt(6) retires S(t+1,Bh1),S(t+1,Ah1) -> certifies
//   next tile's p0 (b23) and p1 (a<-Ah1) reads. All ENTERs drain lgkmcnt(0).
// Stage plan identical to round 6: p0 S(t+1,Ah1); p1 S(t+2,Ah0); p2 S(t+2,Bh0);
// p3 S(t+2,Bh1).  Per-acc MFMA order identical to round 6 -> same absmax.
// LDS XOR-swizzle byte^=(row&7)<<4 via inverse-permuted global source + swizzled reads.
// EPI: 0 = none, 1 = +bias, 2 = relu(+bias)
#define PHASE_ENTER() do {                                    \
    __builtin_amdgcn_sched_barrier(0);                        \
    __builtin_amdgcn_s_barrier();                             \
    asm volatile("s_waitcnt lgkmcnt(0)" ::: "memory");        \
    __builtin_amdgcn_sched_barrier(0);                        \
    __builtin_amdgcn_s_setprio(1);                            \
} while (0)
#define PHASE_EXIT() do {                                     \
    __builtin_amdgcn_s_setprio(0);                            \
    __builtin_amdgcn_sched_barrier(0);                        \
    __builtin_amdgcn_s_barrier();                             \
    __builtin_amdgcn_sched_barrier(0);                        \
} while (0)
#define PHASE_EXIT_VM(n) do {                                 \
    __builtin_amdgcn_s_setprio(0);                            \
    __builtin_amdgcn_sched_barrier(0);                        \
    asm volatile("s_waitcnt vmcnt(" #n ")" ::: "memory");     \
    __builtin_amdgcn_sched_barrier(0);                        \
    __builtin_amdgcn_s_barrier();                             \
    __builtin_amdgcn_sched_barrier(0);                        \
} while (0)

// one (mi,ni) pair: both K-slices, accumulation order identical to round 6
#define MFMA1(MI, NI, AOFF)                                                          \
    acc[(AOFF) + (MI)][(NI)] = __builtin_amdgcn_mfma_f32_16x16x32_bf16(              \
        a[MI][0], b[NI][0], acc[(AOFF) + (MI)][(NI)], 0, 0, 0);                      \
    acc[(AOFF) + (MI)][(NI)] = __builtin_amdgcn_mfma_f32_16x16x32_bf16(              \
        a[MI][1], b[NI][1], acc[(AOFF) + (MI)][(NI)], 0, 0, 0);

#define RD_A2(MI, BASE)                                                              \
    a[MI][0] = *(const bf16x8*)(smemc + (BASE) + (MI) * 4096 + aO0);                 \
    a[MI][1] = *(const bf16x8*)(smemc + (BASE) + (MI) * 4096 + aO1);
#define RD_B2(NI, BASE, SUB)                                                         \
    b[NI][0] = *(const bf16x8*)(smemc + (BASE) + (SUB) + bO0);                       \
    b[NI][1] = *(const bf16x8*)(smemc + (BASE) + (SUB) + bO1);

// One K-tile; P = TT&1, PN = (TT+1)&1 as compile-time constants.
#define KTILE(TT, P, PN)                                                             \
    /* p0: G0(aH0 x b01); interleave b23 <- Bh1(t) */                                \
    stage((TT) + 1, 3);                                                              \
    PHASE_ENTER();                                                                   \
    MFMA1(0, 0, 0) MFMA1(0, 1, 0)                                                    \
    RD_B2(2, (P) * 65536 + 32768, 0)                                                 \
    RD_B2(3, (P) * 65536 + 32768, 8192)                                              \
    MFMA1(1, 0, 0) MFMA1(1, 1, 0) MFMA1(2, 0, 0) MFMA1(2, 1, 0)                      \
    MFMA1(3, 0, 0) MFMA1(3, 1, 0)                                                    \
    PHASE_EXIT();                                                                    \
    /* p1: G1(aH0 x b23); per-mi a[mi] <- Ah1(t) */                                  \
    stage((TT) + 2, 0);                                                              \
    PHASE_ENTER();                                                                   \
    MFMA1(0, 2, 0) MFMA1(0, 3, 0) RD_A2(0, (P) * 65536 + 49152)                      \
    MFMA1(1, 2, 0) MFMA1(1, 3, 0) RD_A2(1, (P) * 65536 + 49152)                      \
    MFMA1(2, 2, 0) MFMA1(2, 3, 0) RD_A2(2, (P) * 65536 + 49152)                      \
    MFMA1(3, 2, 0) MFMA1(3, 3, 0) RD_A2(3, (P) * 65536 + 49152)                      \
    PHASE_EXIT_VM(6);                                                                \
    /* p2: G2(aH1 x b01, acc4+); tail b01 <- Bh0(t+1) */                             \
    stage((TT) + 2, 1);                                                              \
    PHASE_ENTER();                                                                   \
    MFMA1(0, 0, 4) MFMA1(0, 1, 4) MFMA1(1, 0, 4) MFMA1(1, 1, 4)                      \
    MFMA1(2, 0, 4) MFMA1(2, 1, 4) MFMA1(3, 0, 4) MFMA1(3, 1, 4)                      \
    RD_B2(0, (PN) * 65536 + 16384, 0)                                                \
    RD_B2(1, (PN) * 65536 + 16384, 8192)                                             \
    PHASE_EXIT();                                                                    \
    /* p3: G3(aH1 x b23, acc4+); per-mi a[mi] <- Ah0(t+1) */                         \
    stage((TT) + 2, 2);                                                              \
    PHASE_ENTER();                                                                   \
    MFMA1(0, 2, 4) MFMA1(0, 3, 4) RD_A2(0, (PN) * 65536)                             \
    MFMA1(1, 2, 4) MFMA1(1, 3, 4) RD_A2(1, (PN) * 65536)                             \
    MFMA1(2, 2, 4) MFMA1(2, 3, 4) RD_A2(2, (PN) * 65536)                             \
    MFMA1(3, 2, 4) MFMA1(3, 3, 4) RD_A2(3, (PN) * 65536)                             \
    PHASE_EXIT_VM(6);

template <int EPI, typename CT>
__global__ __launch_bounds__(512, 2)
void gemm256(const u16* __restrict__ A, const u16* __restrict__ Bt,
             const float* __restrict__ bias, CT* __restrict__ C,
             int K, int Nreal, int ldc, int nbx) {
    __shared__ __align__(16) u16 smem[65536];   // 128 KiB = 8 slots x 16 KiB

    // XCD-aware block swizzle (guarded: only when grid is a multiple of 8 -> bijective)
    const int nb = (int)gridDim.x;
    int id = (int)blockIdx.x;
    if ((nb & 7) == 0) id = (id & 7) * (nb >> 3) + (id >> 3);
    const int bx = id % nbx, by = id / nbx;
    const size_t row0 = (size_t)by * 256, col0 = (size_t)bx * 256;

    const int t = threadIdx.x;
    const int lane = t & 63, wave = t >> 6;     // 8 waves
    const int wm = wave >> 2, wn = wave & 3;    // 2 x 4
    const int quad = lane >> 4, l16 = lane & 15;
    const int NT = K >> 6;                      // K-tiles of 64 (even for all layers)

    // --- staging source pointers (per thread, insts i=0,1) ---
    const u16* gA[2]; const u16* gB[2];
    #pragma unroll
    for (int i = 0; i < 2; ++i) {
        int c = wave * 128 + i * 64 + lane;
        int lc = c ^ ((c >> 3) & 7);            // chunk-level inverse of byte^=(row&7)<<4
        int srow = lc >> 3, k8 = lc & 7;
        gA[i] = A + (row0 + srow) * (size_t)K + k8 * 8;
        gB[i] = Bt + (col0 + srow) * (size_t)K + k8 * 8;
    }
    const int ldst = wave * 2048;               // this wave's byte base within a slot
    const size_t halfK = (size_t)128 * K;       // element offset of rows 128..255

    auto stage = [&](int tile, int j) {         // j: 0=A.h0 1=B.h0 2=B.h1 3=A.h1
        int tw = tile >= NT ? tile - NT : tile; // wrap past end (data never read)
        const size_t roff = (j >= 2 ? halfK : (size_t)0) + (size_t)tw * 64;
        char* lb = (char*)smem + ((((tile & 1) << 2) + j) << 14) + ldst;
        if (j == 0 || j == 3) {
            gload16(gA[0] + roff, lb);
            gload16(gA[1] + roff, lb + 1024);
        } else {
            gload16(gB[0] + roff, lb);
            gload16(gB[1] + roff, lb + 1024);
        }
    };

    // --- ds_read lane-offset components (slot-relative bytes, swizzled) ---
    const char* smemc = (const char*)smem;
    const int swz = (l16 & 7) << 4;
    const int aO0 = (wm * 16 + l16) * 128 + ((quad * 16) ^ swz);
    const int aO1 = (wm * 16 + l16) * 128 + ((64 + quad * 16) ^ swz);
    const int bO0 = (wn * 16 + l16) * 128 + ((quad * 16) ^ swz);
    const int bO1 = (wn * 16 + l16) * 128 + ((64 + quad * 16) ^ swz);

    floatx4 acc[8][4];
    #pragma unroll
    for (int i = 0; i < 8; ++i)
        #pragma unroll
        for (int j = 0; j < 4; ++j) acc[i][j] = (floatx4){0.f, 0.f, 0.f, 0.f};
    bf16x8 a[4][2], b[4][2];   // round-6 register structure: 64 frag VGPRs, no spill

    // --- prologue: stage halves o0..o6 (tile0 complete + tile1 {Ah0,Bh0,Bh1}) ---
    stage(0, 0); stage(0, 1); stage(0, 2); stage(0, 3);
    __builtin_amdgcn_sched_barrier(0);
    asm volatile("s_waitcnt vmcnt(4)" ::: "memory");
    __builtin_amdgcn_sched_barrier(0);
    stage(1, 0); stage(1, 1); stage(1, 2);
    __builtin_amdgcn_sched_barrier(0);
    asm volatile("s_waitcnt vmcnt(6)" ::: "memory");   // tile 0 fully resident
    __builtin_amdgcn_sched_barrier(0);
    __builtin_amdgcn_s_barrier();
    __builtin_amdgcn_sched_barrier(0);

    // pre-reads (emulate p2/p3 of tile -1): a <- Ah0(0), b01 <- Bh0(0)
    RD_A2(0, 0) RD_A2(1, 0) RD_A2(2, 0) RD_A2(3, 0)
    RD_B2(0, 16384, 0)
    RD_B2(1, 16384, 8192)

    for (int tt = 0; tt < NT; tt += 2) {
        KTILE(tt, 0, 1)
        KTILE(tt + 1, 1, 0)
    }

    // ---- epilogue: C/D layout (m89-verified): col = lane&15, row = quad*4 + r
    #pragma unroll
    for (int ni = 0; ni < 4; ++ni) {
        const int col = (int)col0 + ni * 64 + wn * 16 + l16;
        if (col >= Nreal) continue;
        const float bv = (EPI != 0) ? bias[col] : 0.f;
        #pragma unroll
        for (int mi = 0; mi < 8; ++mi) {
            #pragma unroll
            for (int r = 0; r < 4; ++r) {
                size_t row = row0 + mi * 32 + wm * 16 + quad * 4 + r;
                float v = acc[mi][ni][r] + bv;
                if (EPI == 2) v = fmaxf(v, 0.f);
                if constexpr (sizeof(CT) == 2) C[row * (size_t)ldc + col] = (CT)f2u(v);
                else                           C[row * (size_t)ldc + col] = (CT)v;
            }
        }
    }
}

// 8-wide row load -> f32, for f32 or bf16 source
__device__ __forceinline__ void load8_f(const float* p, float* v) {
    float4 a = *(const float4*)p;
    float4 b = *(const float4*)(p + 4);
    v[0] = a.x; v[1] = a.y; v[2] = a.z; v[3] = a.w;
    v[4] = b.x; v[5] = b.y; v[6] = b.z; v[7] = b.w;
}
__device__ __forceinline__ void load8_b(const u16* p, float* v) {
    uint4 a = *(const uint4*)p;
    const u16* ap = (const u16*)&a;
    #pragma unroll
    for (int j = 0; j < 8; ++j) v[j] = u2f(ap[j]);
}

// ---------- aggregation (pre-GEMM): Xa[i] = dinv2[i]*X[i] + sum_e w_e * X[src_e]; Xa bf16 ----------
template <typename XT>
__global__ __launch_bounds__(256)
void k_agg_pre(const XT* __restrict__ X, const int* __restrict__ off,
               const int* __restrict__ csr_src, const float* __restrict__ csr_w,
               const float* __restrict__ dinv2, u16* __restrict__ Xa, int F) {
    const int i = blockIdx.x;
    const int e0 = off[i], e1 = off[i + 1];
    const float d2 = dinv2[i];
    const int stride = blockDim.x * 8;
    for (int f = threadIdx.x * 8; f < F; f += stride) {
        float acc[8], hv[8];
        if constexpr (sizeof(XT) == 2) load8_b((const u16*)&X[(size_t)i * F + f], hv);
        else                           load8_f((const float*)&X[(size_t)i * F + f], hv);
        #pragma unroll
        for (int j = 0; j < 8; ++j) acc[j] = d2 * hv[j];
        for (int e = e0; e < e1; ++e) {
            int s = csr_src[e];
            float w = csr_w[e];
            float sv[8];
            if constexpr (sizeof(XT) == 2) load8_b((const u16*)&X[(size_t)s * F + f], sv);
            else                           load8_f((const float*)&X[(size_t)s * F + f], sv);
            #pragma unroll
            for (int j = 0; j < 8; ++j) acc[j] = fmaf(w, sv[j], acc[j]);
        }
        uint4 ov;
        u16* op = (u16*)&ov;
        #pragma unroll
        for (int j = 0; j < 8; ++j) op[j] = f2u(acc[j]);
        *(uint4*)&Xa[(size_t)i * F + f] = ov;
    }
}

// ---------- aggregation (post-GEMM): X[i] = relu(b + dinv2[i]*H[i] + sum_e w_e*H[src_e]) ----------
__global__ __launch_bounds__(256)
void k_agg_post(const u16* __restrict__ H, const int* __restrict__ off,
                const int* __restrict__ csr_src, const float* __restrict__ csr_w,
                const float* __restrict__ dinv2, const float* __restrict__ bias,
                u16* __restrict__ X, int F) {
    const int i = blockIdx.x;
    const int e0 = off[i], e1 = off[i + 1];
    const float d2 = dinv2[i];
    const int stride = blockDim.x * 8;
    for (int f = threadIdx.x * 8; f < F; f += stride) {
        float acc[8], hv[8];
        load8_b(&H[(size_t)i * F + f], hv);
        #pragma unroll
        for (int j = 0; j < 8; ++j) acc[j] = fmaf(d2, hv[j], bias[f + j]);
        for (int e = e0; e < e1; ++e) {
            int s = csr_src[e];
            float w = csr_w[e];
            float sv[8];
            load8_b(&H[(size_t)s * F + f], sv);
            #pragma unroll
            for (int j = 0; j < 8; ++j) acc[j] = fmaf(w, sv[j], acc[j]);
        }
        uint4 ov;
        u16* op = (u16*)&ov;
        #pragma unroll
        for (int j = 0; j < 8; ++j) op[j] = f2u(fmaxf(acc[j], 0.f));
        *(uint4*)&X[(size_t)i * F + f] = ov;
    }
}

// ---------------- launch ----------------
extern "C" void kernel_launch(void* const* d_in, const int* in_sizes, int n_in,
                              void* d_out, int out_size, void* d_ws, size_t ws_size,
                              hipStream_t stream) {
    const int N = 16384, E = 65536;
    const float* x   = (const float*)d_in[0];
    const int*   src = (const int*)d_in[1];
    const int*   dst = (const int*)d_in[2];
    const float* ew  = (const float*)d_in[3];
    const float* W[5] = {(const float*)d_in[4], (const float*)d_in[6], (const float*)d_in[8],
                         (const float*)d_in[10], (const float*)d_in[12]};
    const float* b[5] = {(const float*)d_in[5], (const float*)d_in[7], (const float*)d_in[9],
                         (const float*)d_in[11], (const float*)d_in[13]};
    static const int Kd[5] = {512, 1024, 2048, 4096, 2048};   // GEMM K per layer
    static const int Md[5] = {1024, 2048, 4096, 2048, 1000};  // real out cols
    static const int Mp[5] = {1024, 2048, 4096, 2048, 1024};  // padded out cols

    char* ws = (char*)d_ws;
    size_t o = 0;
    auto alloc = [&](size_t bytes) -> void* {
        void* p = ws + o;
        o = (o + bytes + 255) & ~(size_t)255;
        return p;
    };
    u16* P = (u16*)alloc((size_t)N * 4096 * 2);   // 128 MiB
    u16* Q = (u16*)alloc((size_t)N * 2048 * 2);   //  64 MiB
    u16* Wt[5];
    for (int i = 0; i < 5; ++i) Wt[i] = (u16*)alloc((size_t)Mp[i] * Kd[i] * 2);
    float* deg   = (float*)alloc(N * 4);
    float* dinv  = (float*)alloc(N * 4);
    float* dinv2 = (float*)alloc(N * 4);
    int* cnt     = (int*)alloc(N * 4);
    int* cur     = (int*)alloc(N * 4);
    int* off     = (int*)alloc((N + 1) * 4);
    int* csr_src = (int*)alloc(E * 4);
    float* csr_w = (float*)alloc(E * 4);
    (void)ws_size; (void)in_sizes; (void)n_in; (void)out_size;

    // graph prep
    k_fill_f32<<<N / 256, 256, 0, stream>>>(deg, 1.0f, N);
    k_fill_i32<<<N / 256, 256, 0, stream>>>(cnt, 0, N);
    k_fill_i32<<<N / 256, 256, 0, stream>>>(cur, 0, N);
    k_deg_accum<<<E / 256, 256, 0, stream>>>(dst, ew, deg, E);
    k_finish_deg<<<N / 256, 256, 0, stream>>>(deg, dinv, dinv2, N);
    k_count<<<E / 256, 256, 0, stream>>>(dst, cnt, E);
    k_scan<<<1, 1024, 0, stream>>>(cnt, off, N);
    k_fill_csr<<<E / 256, 256, 0, stream>>>(src, dst, ew, dinv, off, cur, csr_src, csr_w, E);

    // weight transposes f32 -> bf16 (pad Wout cols 1000 -> 1024 with zeros)
    for (int i = 0; i < 5; ++i)
        k_transpose<<<dim3(Mp[i] / 32, Kd[i] / 32), dim3(32, 8), 0, stream>>>(W[i], Wt[i], Kd[i], Md[i]);

    const int MT = N / 256;   // 64 row tiles

    // L1..L3: agg-first (A-hat linear => agg(X W) = (agg X) W), bias+relu in GEMM epilogue
    k_agg_pre<float><<<N, 64, 0, stream>>>(x, off, csr_src, csr_w, dinv2, Q, 512);
    gemm256<2, u16><<<dim3((Mp[0] / 256) * MT), 512, 0, stream>>>(Q, Wt[0], b[0], P, Kd[0], Md[0], Md[0], Mp[0] / 256);
    k_agg_pre<u16><<<N, 128, 0, stream>>>(P, off, csr_src, csr_w, dinv2, Q, 1024);
    gemm256<2, u16><<<dim3((Mp[1] / 256) * MT), 512, 0, stream>>>(Q, Wt[1], b[1], P, Kd[1], Md[1], Md[1], Mp[1] / 256);
    k_agg_pre<u16><<<N, 256, 0, stream>>>(P, off, csr_src, csr_w, dinv2, Q, 2048);
    gemm256<2, u16><<<dim3((Mp[2] / 256) * MT), 512, 0, stream>>>(Q, Wt[2], b[2], P, Kd[2], Md[2], Md[2], Mp[2] / 256);
    // L4: GEMM-then-agg (agg at 2048 instead of 4096)
    gemm256<0, u16><<<dim3((Mp[3] / 256) * MT), 512, 0, stream>>>(P, Wt[3], nullptr, Q, Kd[3], Md[3], Md[3], Mp[3] / 256);
    k_agg_post<<<N, 256, 0, stream>>>(Q, off, csr_src, csr_w, dinv2, b[3], P, 2048);
    // L5: output projection -> d_out f32 (Nreal=1000, ldc=1000)
    gemm256<1, float><<<dim3((Mp[4] / 256) * MT), 512, 0, stream>>>(P, Wt[4], b[4], (float*)d_out, Kd[4], Md[4], 1000, Mp[4] / 256);
}

// Round 10
// 969.292 us; speedup vs baseline: 1.5376x; 1.0008x over previous
//
#include <hip/hip_runtime.h>

typedef unsigned short u16;
typedef __bf16 bf16x8 __attribute__((ext_vector_type(8)));
typedef float floatx4 __attribute__((ext_vector_type(4)));

__device__ __forceinline__ float u2f(u16 u) { return __uint_as_float(((unsigned)u) << 16); }
__device__ __forceinline__ u16 f2u(float f) {
    unsigned x = __float_as_uint(f);
    x += 0x7fffu + ((x >> 16) & 1u);   // RNE to bf16
    return (u16)(x >> 16);
}

// ---------------- prep kernels ----------------
__global__ void k_fill_f32(float* p, float v, int n) {
    int i = blockIdx.x * blockDim.x + threadIdx.x;
    if (i < n) p[i] = v;
}
__global__ void k_fill_i32(int* p, int v, int n) {
    int i = blockIdx.x * blockDim.x + threadIdx.x;
    if (i < n) p[i] = v;
}
__global__ void k_deg_accum(const int* __restrict__ dst, const float* __restrict__ ew,
                            float* __restrict__ deg, int E) {
    int e = blockIdx.x * blockDim.x + threadIdx.x;
    if (e < E) atomicAdd(&deg[dst[e]], ew[e]);
}
__global__ void k_finish_deg(const float* __restrict__ deg, float* __restrict__ dinv,
                             float* __restrict__ dinv2, int n) {
    int i = blockIdx.x * blockDim.x + threadIdx.x;
    if (i < n) { float r = rsqrtf(deg[i]); dinv[i] = r; dinv2[i] = r * r; }
}
__global__ void k_count(const int* __restrict__ dst, int* __restrict__ cnt, int E) {
    int e = blockIdx.x * blockDim.x + threadIdx.x;
    if (e < E) atomicAdd(&cnt[dst[e]], 1);
}
// single-block exclusive scan over n=16384 counts -> off[0..n]
__global__ void k_scan(const int* __restrict__ cnt, int* __restrict__ off, int n) {
    __shared__ int sh[1024];
    int t = threadIdx.x;
    const int per = n / 1024;   // 16
    int base = t * per;
    int loc[16];
    int s = 0;
    for (int j = 0; j < per; ++j) { loc[j] = s; s += cnt[base + j]; }
    sh[t] = s;
    __syncthreads();
    for (int d = 1; d < 1024; d <<= 1) {
        int v = (t >= d) ? sh[t - d] : 0;
        __syncthreads();
        sh[t] += v;
        __syncthreads();
    }
    int prev = (t == 0) ? 0 : sh[t - 1];
    for (int j = 0; j < per; ++j) off[base + j] = prev + loc[j];
    if (t == 1023) off[n] = prev + s;
}
__global__ void k_fill_csr(const int* __restrict__ src, const int* __restrict__ dst,
                           const float* __restrict__ ew, const float* __restrict__ dinv,
                           const int* __restrict__ off, int* __restrict__ cur,
                           int* __restrict__ csr_src, float* __restrict__ csr_w, int E) {
    int e = blockIdx.x * blockDim.x + threadIdx.x;
    if (e < E) {
        int d = dst[e], s = src[e];
        int p = off[d] + atomicAdd(&cur[d], 1);
        csr_src[p] = s;
        csr_w[p] = dinv[s] * ew[e] * dinv[d];
    }
}
// W[K][M] (f32) -> Wt[Mpad][K] (bf16), zero-filled for m >= M. grid(Mpad/32, K/32), block(32,8)
__global__ void k_transpose(const float* __restrict__ W, u16* __restrict__ Wt, int K, int M) {
    __shared__ u16 tile[32][33];
    int m0 = blockIdx.x * 32, k0 = blockIdx.y * 32;
    int tx = threadIdx.x, ty = threadIdx.y;
    #pragma unroll
    for (int rr = 0; rr < 4; ++rr) {
        int r = ty + rr * 8;
        int m = m0 + tx, k = k0 + r;
        tile[r][tx] = (m < M) ? f2u(W[(size_t)k * M + m]) : (u16)0;
    }
    __syncthreads();
    #pragma unroll
    for (int rr = 0; rr < 4; ++rr) {
        int r = ty + rr * 8;
        Wt[(size_t)(m0 + r) * K + k0 + tx] = tile[tx][r];
    }
}

// ---------------- async global -> LDS (16B/lane, wave-uniform LDS base) ----------------
__device__ __forceinline__ void gload16(const u16* g, void* l) {
    typedef __attribute__((address_space(1))) void* gas_t;
    typedef __attribute__((address_space(3))) void* las_t;
    __builtin_amdgcn_global_load_lds((gas_t)g, (las_t)l, 16, 0, 0);
}

// ---------------- GEMM: C[16384 x Nreal] = A[16384 x K] * Bt[Npad x K]^T ----------------
// 256x256 tile, BK=64, 8 waves (2Mx4N at 16-granularity), 128 KiB LDS as 8 half-tile
// slots of 16 KiB.  ONE barrier per phase (4/tile, was 8): the exit barrier is
// removed; safety re-derived:
//  WAR rule: every LDS-slot overwrite (stage) is issued >=2 barriers after the
//  slot's last reads were issued -- any wave at barrier(p+2) has executed the
//  lgkmcnt(0) at enter(p+1), so those reads are retired.  Stage placement:
//    end-p0: S(t+2,Bh0)  [slot last read p2(t-1); barriers p3,p0 intervene]
//    end-p1: S(t+2,Ah0)  [last read p3(t-1); barriers p0,p1]
//    end-p2: S(t+2,Bh1)  [last read p0(t);   barriers p1,p2]
//    end-p3: S(t+2,Ah1)  [last read p1(t);   barriers p2,p3]
//  RAW rule: issuer-vmcnt BEFORE the publishing barrier.  vmcnt(8) at end-p1
//  retires S(t+1,Bh0),S(t+1,Ah0) -> p2's b01<-Bh0(t+1) and p3's a<-Ah0(t+1);
//  vmcnt(8) at end-p3 retires S(t+1,Bh1),S(t+1,Ah1) -> next p0's b23 and p1's a.
//  Both certify loads issued 5-6 phases prior -> stall-free; never drained to 0.
// Reads stay WAR-interleaved inside MFMA clusters (round-8 structure, registers
// unchanged: a[4][2], b[4][2]).  Per-acc MFMA order identical -> same absmax.
// LDS XOR-swizzle byte^=(row&7)<<4 via inverse-permuted global source + swizzled reads.
// EPI: 0 = none, 1 = +bias, 2 = relu(+bias)
#define PH_SYNC() do {                                        \
    __builtin_amdgcn_sched_barrier(0);                        \
    __builtin_amdgcn_s_barrier();                             \
    asm volatile("s_waitcnt lgkmcnt(0)" ::: "memory");        \
    __builtin_amdgcn_sched_barrier(0);                        \
    __builtin_amdgcn_s_setprio(1);                            \
} while (0)
#define PH_END() do {                                         \
    __builtin_amdgcn_s_setprio(0);                            \
    __builtin_amdgcn_sched_barrier(0);                        \
} while (0)
#define VMW(n) do {                                           \
    asm volatile("s_waitcnt vmcnt(" #n ")" ::: "memory");     \
    __builtin_amdgcn_sched_barrier(0);                        \
} while (0)

// one (mi,ni) pair: both K-slices, accumulation order identical to round 8
#define MFMA1(MI, NI, AOFF)                                                          \
    acc[(AOFF) + (MI)][(NI)] = __builtin_amdgcn_mfma_f32_16x16x32_bf16(              \
        a[MI][0], b[NI][0], acc[(AOFF) + (MI)][(NI)], 0, 0, 0);                      \
    acc[(AOFF) + (MI)][(NI)] = __builtin_amdgcn_mfma_f32_16x16x32_bf16(              \
        a[MI][1], b[NI][1], acc[(AOFF) + (MI)][(NI)], 0, 0, 0);

#define RD_A2(MI, BASE)                                                              \
    a[MI][0] = *(const bf16x8*)(smemc + (BASE) + (MI) * 4096 + aO0);                 \
    a[MI][1] = *(const bf16x8*)(smemc + (BASE) + (MI) * 4096 + aO1);
#define RD_B2(NI, BASE, SUB)                                                         \
    b[NI][0] = *(const bf16x8*)(smemc + (BASE) + (SUB) + bO0);                       \
    b[NI][1] = *(const bf16x8*)(smemc + (BASE) + (SUB) + bO1);

// One K-tile; P = TT&1, PN = (TT+1)&1 as compile-time constants.
#define KTILE(TT, P, PN)                                                             \
    /* p0: G0(aH0 x b01); interleave b23 <- Bh1(t) */                                \
    PH_SYNC();                                                                       \
    MFMA1(0, 0, 0) MFMA1(0, 1, 0)                                                    \
    RD_B2(2, (P) * 65536 + 32768, 0)                                                 \
    RD_B2(3, (P) * 65536 + 32768, 8192)                                              \
    MFMA1(1, 0, 0) MFMA1(1, 1, 0) MFMA1(2, 0, 0) MFMA1(2, 1, 0)                      \
    MFMA1(3, 0, 0) MFMA1(3, 1, 0)                                                    \
    PH_END();                                                                        \
    stage((TT) + 2, 1);                                                              \
    /* p1: G1(aH0 x b23); per-mi a[mi] <- Ah1(t) */                                  \
    PH_SYNC();                                                                       \
    MFMA1(0, 2, 0) MFMA1(0, 3, 0) RD_A2(0, (P) * 65536 + 49152)                      \
    MFMA1(1, 2, 0) MFMA1(1, 3, 0) RD_A2(1, (P) * 65536 + 49152)                      \
    MFMA1(2, 2, 0) MFMA1(2, 3, 0) RD_A2(2, (P) * 65536 + 49152)                      \
    MFMA1(3, 2, 0) MFMA1(3, 3, 0) RD_A2(3, (P) * 65536 + 49152)                      \
    PH_END();                                                                        \
    stage((TT) + 2, 0);                                                              \
    VMW(8);                                                                          \
    /* p2: G2(aH1 x b01, acc4+); tail b01 <- Bh0(t+1) */                             \
    PH_SYNC();                                                                       \
    MFMA1(0, 0, 4) MFMA1(0, 1, 4) MFMA1(1, 0, 4) MFMA1(1, 1, 4)                      \
    MFMA1(2, 0, 4) MFMA1(2, 1, 4) MFMA1(3, 0, 4) MFMA1(3, 1, 4)                      \
    RD_B2(0, (PN) * 65536 + 16384, 0)                                                \
    RD_B2(1, (PN) * 65536 + 16384, 8192)                                             \
    PH_END();                                                                        \
    stage((TT) + 2, 2);                                                              \
    /* p3: G3(aH1 x b23, acc4+); per-mi a[mi] <- Ah0(t+1) */                         \
    PH_SYNC();                                                                       \
    MFMA1(0, 2, 4) MFMA1(0, 3, 4) RD_A2(0, (PN) * 65536)                             \
    MFMA1(1, 2, 4) MFMA1(1, 3, 4) RD_A2(1, (PN) * 65536)                             \
    MFMA1(2, 2, 4) MFMA1(2, 3, 4) RD_A2(2, (PN) * 65536)                             \
    MFMA1(3, 2, 4) MFMA1(3, 3, 4) RD_A2(3, (PN) * 65536)                             \
    PH_END();                                                                        \
    stage((TT) + 2, 3);                                                              \
    VMW(8);

template <int EPI, typename CT>
__global__ __launch_bounds__(512, 2)
void gemm256(const u16* __restrict__ A, const u16* __restrict__ Bt,
             const float* __restrict__ bias, CT* __restrict__ C,
             int K, int Nreal, int ldc, int nbx) {
    __shared__ __align__(16) u16 smem[65536];   // 128 KiB = 8 slots x 16 KiB

    // XCD-aware block swizzle (guarded: only when grid is a multiple of 8 -> bijective)
    const int nb = (int)gridDim.x;
    int id = (int)blockIdx.x;
    if ((nb & 7) == 0) id = (id & 7) * (nb >> 3) + (id >> 3);
    const int bx = id % nbx, by = id / nbx;
    const size_t row0 = (size_t)by * 256, col0 = (size_t)bx * 256;

    const int t = threadIdx.x;
    const int lane = t & 63, wave = t >> 6;     // 8 waves
    const int wm = wave >> 2, wn = wave & 3;    // 2 x 4
    const int quad = lane >> 4, l16 = lane & 15;
    const int NT = K >> 6;                      // K-tiles of 64 (even for all layers)

    // --- staging source pointers (per thread, insts i=0,1) ---
    const u16* gA[2]; const u16* gB[2];
    #pragma unroll
    for (int i = 0; i < 2; ++i) {
        int c = wave * 128 + i * 64 + lane;
        int lc = c ^ ((c >> 3) & 7);            // chunk-level inverse of byte^=(row&7)<<4
        int srow = lc >> 3, k8 = lc & 7;
        gA[i] = A + (row0 + srow) * (size_t)K + k8 * 8;
        gB[i] = Bt + (col0 + srow) * (size_t)K + k8 * 8;
    }
    const int ldst = wave * 2048;               // this wave's byte base within a slot
    const size_t halfK = (size_t)128 * K;       // element offset of rows 128..255

    auto stage = [&](int tile, int j) {         // j: 0=A.h0 1=B.h0 2=B.h1 3=A.h1
        int tw = tile >= NT ? tile - NT : tile; // wrap past end (data never read)
        const size_t roff = (j >= 2 ? halfK : (size_t)0) + (size_t)tw * 64;
        char* lb = (char*)smem + ((((tile & 1) << 2) + j) << 14) + ldst;
        if (j == 0 || j == 3) {
            gload16(gA[0] + roff, lb);
            gload16(gA[1] + roff, lb + 1024);
        } else {
            gload16(gB[0] + roff, lb);
            gload16(gB[1] + roff, lb + 1024);
        }
    };

    // --- ds_read lane-offset components (slot-relative bytes, swizzled) ---
    const char* smemc = (const char*)smem;
    const int swz = (l16 & 7) << 4;
    const int aO0 = (wm * 16 + l16) * 128 + ((quad * 16) ^ swz);
    const int aO1 = (wm * 16 + l16) * 128 + ((64 + quad * 16) ^ swz);
    const int bO0 = (wn * 16 + l16) * 128 + ((quad * 16) ^ swz);
    const int bO1 = (wn * 16 + l16) * 128 + ((64 + quad * 16) ^ swz);

    floatx4 acc[8][4];
    #pragma unroll
    for (int i = 0; i < 8; ++i)
        #pragma unroll
        for (int j = 0; j < 4; ++j) acc[i][j] = (floatx4){0.f, 0.f, 0.f, 0.f};
    bf16x8 a[4][2], b[4][2];   // round-8 register structure: 64 frag VGPRs, no spill

    // --- prologue: tile 0 staged+published, pre-reads, then S(1,*) in steady-state order
    stage(0, 0); stage(0, 1); stage(0, 2); stage(0, 3);
    __builtin_amdgcn_sched_barrier(0);
    asm volatile("s_waitcnt vmcnt(0)" ::: "memory");
    __builtin_amdgcn_sched_barrier(0);
    __builtin_amdgcn_s_barrier();
    __builtin_amdgcn_sched_barrier(0);

    // pre-reads (emulate p2/p3 of tile -1): a <- Ah0(0), b01 <- Bh0(0)
    RD_A2(0, 0) RD_A2(1, 0) RD_A2(2, 0) RD_A2(3, 0)
    RD_B2(0, 16384, 0)
    RD_B2(1, 16384, 8192)
    __builtin_amdgcn_sched_barrier(0);
    // issue S(1,*) in steady-state order {Bh0, Ah0, Bh1, Ah1} -> 8 outstanding
    stage(1, 1); stage(1, 0); stage(1, 2); stage(1, 3);
    VMW(8);   // no-op; establishes the ledger invariant entering the loop

    for (int tt = 0; tt < NT; tt += 2) {
        KTILE(tt, 0, 1)
        KTILE(tt + 1, 1, 0)
    }

    // ---- epilogue: C/D layout (m89-verified): col = lane&15, row = quad*4 + r
    #pragma unroll
    for (int ni = 0; ni < 4; ++ni) {
        const int col = (int)col0 + ni * 64 + wn * 16 + l16;
        if (col >= Nreal) continue;
        const float bv = (EPI != 0) ? bias[col] : 0.f;
        #pragma unroll
        for (int mi = 0; mi < 8; ++mi) {
            #pragma unroll
            for (int r = 0; r < 4; ++r) {
                size_t row = row0 + mi * 32 + wm * 16 + quad * 4 + r;
                float v = acc[mi][ni][r] + bv;
                if (EPI == 2) v = fmaxf(v, 0.f);
                if constexpr (sizeof(CT) == 2) C[row * (size_t)ldc + col] = (CT)f2u(v);
                else                           C[row * (size_t)ldc + col] = (CT)v;
            }
        }
    }
}

// 8-wide row load -> f32, for f32 or bf16 source
__device__ __forceinline__ void load8_f(const float* p, float* v) {
    float4 a = *(const float4*)p;
    float4 b = *(const float4*)(p + 4);
    v[0] = a.x; v[1] = a.y; v[2] = a.z; v[3] = a.w;
    v[4] = b.x; v[5] = b.y; v[6] = b.z; v[7] = b.w;
}
__device__ __forceinline__ void load8_b(const u16* p, float* v) {
    uint4 a = *(const uint4*)p;
    const u16* ap = (const u16*)&a;
    #pragma unroll
    for (int j = 0; j < 8; ++j) v[j] = u2f(ap[j]);
}

// ---------- aggregation (pre-GEMM): Xa[i] = dinv2[i]*X[i] + sum_e w_e * X[src_e]; Xa bf16 ----------
template <typename XT>
__global__ __launch_bounds__(256)
void k_agg_pre(const XT* __restrict__ X, const int* __restrict__ off,
               const int* __restrict__ csr_src, const float* __restrict__ csr_w,
               const float* __restrict__ dinv2, u16* __restrict__ Xa, int F) {
    const int i = blockIdx.x;
    const int e0 = off[i], e1 = off[i + 1];
    const float d2 = dinv2[i];
    const int stride = blockDim.x * 8;
    for (int f = threadIdx.x * 8; f < F; f += stride) {
        float acc[8], hv[8];
        if constexpr (sizeof(XT) == 2) load8_b((const u16*)&X[(size_t)i * F + f], hv);
        else                           load8_f((const float*)&X[(size_t)i * F + f], hv);
        #pragma unroll
        for (int j = 0; j < 8; ++j) acc[j] = d2 * hv[j];
        for (int e = e0; e < e1; ++e) {
            int s = csr_src[e];
            float w = csr_w[e];
            float sv[8];
            if constexpr (sizeof(XT) == 2) load8_b((const u16*)&X[(size_t)s * F + f], sv);
            else                           load8_f((const float*)&X[(size_t)s * F + f], sv);
            #pragma unroll
            for (int j = 0; j < 8; ++j) acc[j] = fmaf(w, sv[j], acc[j]);
        }
        uint4 ov;
        u16* op = (u16*)&ov;
        #pragma unroll
        for (int j = 0; j < 8; ++j) op[j] = f2u(acc[j]);
        *(uint4*)&Xa[(size_t)i * F + f] = ov;
    }
}

// ---------- aggregation (post-GEMM): X[i] = relu(b + dinv2[i]*H[i] + sum_e w_e*H[src_e]) ----------
__global__ __launch_bounds__(256)
void k_agg_post(const u16* __restrict__ H, const int* __restrict__ off,
                const int* __restrict__ csr_src, const float* __restrict__ csr_w,
                const float* __restrict__ dinv2, const float* __restrict__ bias,
                u16* __restrict__ X, int F) {
    const int i = blockIdx.x;
    const int e0 = off[i], e1 = off[i + 1];
    const float d2 = dinv2[i];
    const int stride = blockDim.x * 8;
    for (int f = threadIdx.x * 8; f < F; f += stride) {
        float acc[8], hv[8];
        load8_b(&H[(size_t)i * F + f], hv);
        #pragma unroll
        for (int j = 0; j < 8; ++j) acc[j] = fmaf(d2, hv[j], bias[f + j]);
        for (int e = e0; e < e1; ++e) {
            int s = csr_src[e];
            float w = csr_w[e];
            float sv[8];
            load8_b(&H[(size_t)s * F + f], sv);
            #pragma unroll
            for (int j = 0; j < 8; ++j) acc[j] = fmaf(w, sv[j], acc[j]);
        }
        uint4 ov;
        u16* op = (u16*)&ov;
        #pragma unroll
        for (int j = 0; j < 8; ++j) op[j] = f2u(fmaxf(acc[j], 0.f));
        *(uint4*)&X[(size_t)i * F + f] = ov;
    }
}

// ---------------- launch ----------------
extern "C" void kernel_launch(void* const* d_in, const int* in_sizes, int n_in,
                              void* d_out, int out_size, void* d_ws, size_t ws_size,
                              hipStream_t stream) {
    const int N = 16384, E = 65536;
    const float* x   = (const float*)d_in[0];
    const int*   src = (const int*)d_in[1];
    const int*   dst = (const int*)d_in[2];
    const float* ew  = (const float*)d_in[3];
    const float* W[5] = {(const float*)d_in[4], (const float*)d_in[6], (const float*)d_in[8],
                         (const float*)d_in[10], (const float*)d_in[12]};
    const float* b[5] = {(const float*)d_in[5], (const float*)d_in[7], (const float*)d_in[9],
                         (const float*)d_in[11], (const float*)d_in[13]};
    static const int Kd[5] = {512, 1024, 2048, 4096, 2048};   // GEMM K per layer
    static const int Md[5] = {1024, 2048, 4096, 2048, 1000};  // real out cols
    static const int Mp[5] = {1024, 2048, 4096, 2048, 1024};  // padded out cols

    char* ws = (char*)d_ws;
    size_t o = 0;
    auto alloc = [&](size_t bytes) -> void* {
        void* p = ws + o;
        o = (o + bytes + 255) & ~(size_t)255;
        return p;
    };
    u16* P = (u16*)alloc((size_t)N * 4096 * 2);   // 128 MiB
    u16* Q = (u16*)alloc((size_t)N * 2048 * 2);   //  64 MiB
    u16* Wt[5];
    for (int i = 0; i < 5; ++i) Wt[i] = (u16*)alloc((size_t)Mp[i] * Kd[i] * 2);
    float* deg   = (float*)alloc(N * 4);
    float* dinv  = (float*)alloc(N * 4);
    float* dinv2 = (float*)alloc(N * 4);
    int* cnt     = (int*)alloc(N * 4);
    int* cur     = (int*)alloc(N * 4);
    int* off     = (int*)alloc((N + 1) * 4);
    int* csr_src = (int*)alloc(E * 4);
    float* csr_w = (float*)alloc(E * 4);
    (void)ws_size; (void)in_sizes; (void)n_in; (void)out_size;

    // graph prep
    k_fill_f32<<<N / 256, 256, 0, stream>>>(deg, 1.0f, N);
    k_fill_i32<<<N / 256, 256, 0, stream>>>(cnt, 0, N);
    k_fill_i32<<<N / 256, 256, 0, stream>>>(cur, 0, N);
    k_deg_accum<<<E / 256, 256, 0, stream>>>(dst, ew, deg, E);
    k_finish_deg<<<N / 256, 256, 0, stream>>>(deg, dinv, dinv2, N);
    k_count<<<E / 256, 256, 0, stream>>>(dst, cnt, E);
    k_scan<<<1, 1024, 0, stream>>>(cnt, off, N);
    k_fill_csr<<<E / 256, 256, 0, stream>>>(src, dst, ew, dinv, off, cur, csr_src, csr_w, E);

    // weight transposes f32 -> bf16 (pad Wout cols 1000 -> 1024 with zeros)
    for (int i = 0; i < 5; ++i)
        k_transpose<<<dim3(Mp[i] / 32, Kd[i] / 32), dim3(32, 8), 0, stream>>>(W[i], Wt[i], Kd[i], Md[i]);

    const int MT = N / 256;   // 64 row tiles

    // L1..L3: agg-first (A-hat linear => agg(X W) = (agg X) W), bias+relu in GEMM epilogue
    k_agg_pre<float><<<N, 64, 0, stream>>>(x, off, csr_src, csr_w, dinv2, Q, 512);
    gemm256<2, u16><<<dim3((Mp[0] / 256) * MT), 512, 0, stream>>>(Q, Wt[0], b[0], P, Kd[0], Md[0], Md[0], Mp[0] / 256);
    k_agg_pre<u16><<<N, 128, 0, stream>>>(P, off, csr_src, csr_w, dinv2, Q, 1024);
    gemm256<2, u16><<<dim3((Mp[1] / 256) * MT), 512, 0, stream>>>(Q, Wt[1], b[1], P, Kd[1], Md[1], Md[1], Mp[1] / 256);
    k_agg_pre<u16><<<N, 256, 0, stream>>>(P, off, csr_src, csr_w, dinv2, Q, 2048);
    gemm256<2, u16><<<dim3((Mp[2] / 256) * MT), 512, 0, stream>>>(Q, Wt[2], b[2], P, Kd[2], Md[2], Md[2], Mp[2] / 256);
    // L4: GEMM-then-agg (agg at 2048 instead of 4096)
    gemm256<0, u16><<<dim3((Mp[3] / 256) * MT), 512, 0, stream>>>(P, Wt[3], nullptr, Q, Kd[3], Md[3], Md[3], Mp[3] / 256);
    k_agg_post<<<N, 256, 0, stream>>>(Q, off, csr_src, csr_w, dinv2, b[3], P, 2048);
    // L5: output projection -> d_out f32 (Nreal=1000, ldc=1000)
    gemm256<1, float><<<dim3((Mp[4] / 256) * MT), 512, 0, stream>>>(P, Wt[4], b[4], (float*)d_out, Kd[4], Md[4], 1000, Mp[4] / 256);
}